// Round 1
// 1029.387 us; speedup vs baseline: 1.1349x; 1.1349x over previous
//
#include <hip/hip_runtime.h>
#include <math.h>

// Problem constants
#define NB   256      // batch rows
#define DIN  5000
#define NH1  2048
#define NH2  1024
#define NISO 100000
#define NG   25000

typedef __attribute__((ext_vector_type(8))) short bf16x8;
typedef __attribute__((ext_vector_type(4))) float f32x4;

__device__ __forceinline__ unsigned short f2bf_rn(float f) {
  union { float f; unsigned u; } v; v.f = f;
  unsigned r = v.u + 0x7FFFu + ((v.u >> 16) & 1u);
  return (unsigned short)(r >> 16);
}
__device__ __forceinline__ float bf2f(unsigned short h) {
  union { unsigned u; float f; } v; v.u = ((unsigned)h) << 16;
  return v.f;
}

// ---------------------------------------------------------------------------
// Split-bf16 (3-term) GEMM: ~fp32 accuracy via hi/lo decomposition.
// A [M x K] row-major fp32, B [K x N] row-major fp32.
// Each blockIdx.z writes its own C slab (no atomics, no zero-init needed);
// the LN kernel sums the slabs.
// grid = (N/BN, M/64, nz), block = 256 (4 waves x 16 rows). BM fixed at 64.
// ---------------------------------------------------------------------------
template<int BN>
__global__ __launch_bounds__(256) void gemm_split(
    const float* __restrict__ A, const float* __restrict__ Bg,
    float* __restrict__ C, int M, int N, int K, int KC)
{
  constexpr int BM = 64;
  constexpr int BK = 32;
  constexpr int LDT = BK + 8;       // pad keeps b128 alignment, breaks pow2 stride
  constexpr int CT = BN / 16;
  __shared__ unsigned short Ah[BM][LDT], Al[BM][LDT];
  __shared__ unsigned short Bh[BN][LDT], Bl[BN][LDT];
  const int tid = threadIdx.x;
  const int wave = tid >> 6, lane = tid & 63;
  const int fr = lane & 15, fq = lane >> 4;
  const int n0 = blockIdx.x * BN, m0 = blockIdx.y * BM;
  const int kb0 = blockIdx.z * KC;
  const int ke = min(kb0 + KC, K);
  const int mrow = wave * 16;
  float* Cz = C + (size_t)blockIdx.z * M * N;

  f32x4 acc[CT];
#pragma unroll
  for (int i = 0; i < CT; i++) acc[i] = (f32x4){0.f, 0.f, 0.f, 0.f};

  for (int kb = kb0; kb < ke; kb += BK) {
    // stage A tile (BM x 32) -> hi/lo, layout [m][k]
    for (int s = tid; s < BM * 8; s += 256) {
      int m = s >> 3, kq = (s & 7) * 4;
      int gk = kb + kq;
      const float* ap = A + (size_t)(m0 + m) * K + gk;
      float4 v;
      if (gk + 3 < ke) v = *(const float4*)ap;
      else {
        v.x = (gk     < ke) ? ap[0] : 0.f;
        v.y = (gk + 1 < ke) ? ap[1] : 0.f;
        v.z = (gk + 2 < ke) ? ap[2] : 0.f;
        v.w = (gk + 3 < ke) ? ap[3] : 0.f;
      }
      unsigned short h0 = f2bf_rn(v.x), h1 = f2bf_rn(v.y),
                     h2 = f2bf_rn(v.z), h3 = f2bf_rn(v.w);
      *(ushort4*)&Ah[m][kq] = make_ushort4(h0, h1, h2, h3);
      *(ushort4*)&Al[m][kq] = make_ushort4(f2bf_rn(v.x - bf2f(h0)),
                                           f2bf_rn(v.y - bf2f(h1)),
                                           f2bf_rn(v.z - bf2f(h2)),
                                           f2bf_rn(v.w - bf2f(h3)));
    }
    // stage B tile (32 x BN) transposed to [n][k] -> hi/lo
    for (int s = tid; s < BN * 8; s += 256) {
      int n = s % BN, k0 = (s / BN) * 4;
      unsigned short hh[4], ll[4];
#pragma unroll
      for (int j = 0; j < 4; j++) {
        int gk = kb + k0 + j;
        float v = (gk < ke) ? Bg[(size_t)gk * N + n0 + n] : 0.f;
        hh[j] = f2bf_rn(v);
        ll[j] = f2bf_rn(v - bf2f(hh[j]));
      }
      *(ushort4*)&Bh[n][k0] = make_ushort4(hh[0], hh[1], hh[2], hh[3]);
      *(ushort4*)&Bl[n][k0] = make_ushort4(ll[0], ll[1], ll[2], ll[3]);
    }
    __syncthreads();
    bf16x8 ah = *(const bf16x8*)&Ah[mrow + fr][fq * 8];
    bf16x8 al = *(const bf16x8*)&Al[mrow + fr][fq * 8];
#pragma unroll
    for (int ct = 0; ct < CT; ct++) {
      bf16x8 bh = *(const bf16x8*)&Bh[ct * 16 + fr][fq * 8];
      bf16x8 bl = *(const bf16x8*)&Bl[ct * 16 + fr][fq * 8];
      acc[ct] = __builtin_amdgcn_mfma_f32_16x16x32_bf16(ah, bh, acc[ct], 0, 0, 0);
      acc[ct] = __builtin_amdgcn_mfma_f32_16x16x32_bf16(ah, bl, acc[ct], 0, 0, 0);
      acc[ct] = __builtin_amdgcn_mfma_f32_16x16x32_bf16(al, bh, acc[ct], 0, 0, 0);
    }
    __syncthreads();
  }
  // epilogue: C/D layout col=lane&15, row=(lane>>4)*4+i ; plain stores
#pragma unroll
  for (int ct = 0; ct < CT; ct++) {
    int c = n0 + ct * 16 + fr;
    int r0 = m0 + mrow + fq * 4;
#pragma unroll
    for (int i = 0; i < 4; i++)
      Cz[(size_t)(r0 + i) * N + c] = acc[ct][i];
  }
}

// ---------------------------------------------------------------------------
// LayerNorm over summed split-K slabs (+bias, biased var, eps=1e-5) + exact
// GELU. One block (256 thr) per row. BF16OUT writes bf16 (consumed only by
// gemm3's A-fragment loads -> saves 1250x redundant fp32->bf16 conversion).
// ---------------------------------------------------------------------------
template<bool BF16OUT>
__global__ __launch_bounds__(256) void ln_gelu_sum(
    const float* __restrict__ slabs, int nslab,
    const float* __restrict__ bias, const float* __restrict__ gam,
    const float* __restrict__ beta, void* __restrict__ outp, int n)
{
  const int r = blockIdx.x;
  float vv[8];
  float s = 0.f, s2 = 0.f;
  int cnt = 0;
  for (int j = threadIdx.x; j < n; j += 256, cnt++) {
    float v = bias[j];
    for (int z = 0; z < nslab; z++)
      v += slabs[((size_t)z * NB + r) * n + j];
    vv[cnt] = v;
    s += v; s2 += v * v;
  }
#pragma unroll
  for (int o = 32; o > 0; o >>= 1) {
    s  += __shfl_down(s, o);
    s2 += __shfl_down(s2, o);
  }
  __shared__ float red[8];
  const int wave = threadIdx.x >> 6, lane = threadIdx.x & 63;
  if (lane == 0) { red[wave] = s; red[wave + 4] = s2; }
  __syncthreads();
  if (threadIdx.x == 0) {
    float ts = 0.f, t2 = 0.f;
    for (int w = 0; w < 4; w++) { ts += red[w]; t2 += red[w + 4]; }
    float mu = ts / n;
    float var = t2 / n - mu * mu;
    red[0] = mu; red[1] = rsqrtf(var + 1e-5f);
  }
  __syncthreads();
  const float mu = red[0], rs = red[1];
  cnt = 0;
  for (int j = threadIdx.x; j < n; j += 256, cnt++) {
    float v = (vv[cnt] - mu) * rs * gam[j] + beta[j];
    float g = 0.5f * v * (1.f + erff(v * 0.70710678118654752f));
    if (BF16OUT) ((unsigned short*)outp)[(size_t)r * n + j] = f2bf_rn(g);
    else         ((float*)outp)[(size_t)r * n + j] = g;
  }
}

// ---------------------------------------------------------------------------
// GEMM3 v2 (memory-bound): h2b[256x1024 bf16] @ W3[1024x100000 fp32] + b3,
// epilogue writes exp(logit) (global row-max shift cancels per-gene).
//  - A read directly from global as MFMA fragments (512 KB, L2-resident:
//    no LDS staging, no per-block re-conversion).
//  - B double-buffered in LDS with async-STAGE split (T14): issue tile t+1
//    fp32 loads -> compute tile t -> convert+ds_write. One barrier/K-tile.
//  - LDT=136 shorts (272 B rows): b128 fragment reads perfectly
//    bank-group balanced ((17n+4ks+fq)%8 == (n+4ks+fq)%8, uniform).
// BM=256 (full M: W3 streamed exactly once), BN=80 -> 1250 blocks, BK=128.
// ---------------------------------------------------------------------------
template<int BN>
__global__ __launch_bounds__(512, 4) void gemm3_exp(
    const unsigned short* __restrict__ Ab,  // h2 bf16 [256][1024]
    const float* __restrict__ Bg,           // W3
    const float* __restrict__ b3,
    float* __restrict__ E)                  // d_out, holds exp(logits)
{
  constexpr int BM = 256, BK = 128, K = NH2, N = NISO;
  constexpr int LDT = BK + 8;       // 136 shorts = 272 B row stride
  constexpr int CT = BN / 16;       // 5
  constexpr int NT = K / BK;        // 8 K-tiles
  constexpr int BUFS = BN * LDT;    // shorts per buffer
  __shared__ unsigned short Bs[2][BN][LDT];   // 2 x 21.25 KB = 42.5 KB
  const int tid = threadIdx.x;
  const int wave = tid >> 6, lane = tid & 63;
  const int fr = lane & 15, fq = lane >> 4;
  const int n0 = blockIdx.x * BN;
  const int mrow = wave * 32;       // 8 waves x 32 rows

  // B staging assignment: s = tid + i*512 in [0, BN*BK/4): n = s%BN (global
  // loads coalesce along n), k4 = s/BN (4 consecutive k rows per task).
  const float* bp[5];
  int woff[5];
#pragma unroll
  for (int i = 0; i < 5; i++) {
    int s = tid + i * 512;
    int n = s % BN, k4 = s / BN;
    bp[i] = Bg + (size_t)(4 * k4) * N + n0 + n;
    woff[i] = n * LDT + k4 * 4;
  }
  unsigned short* const bs0 = &Bs[0][0][0];
  float bv[5][4];

  f32x4 acc[2][CT];
#pragma unroll
  for (int r = 0; r < 2; r++)
#pragma unroll
    for (int c = 0; c < CT; c++) acc[r][c] = (f32x4){0.f, 0.f, 0.f, 0.f};

  // prologue: tile 0 -> regs -> LDS buf0
#pragma unroll
  for (int i = 0; i < 5; i++) {
    const float* p = bp[i];
    bv[i][0] = p[0]; bv[i][1] = p[N];
    bv[i][2] = p[2 * (size_t)N]; bv[i][3] = p[3 * (size_t)N];
    bp[i] += (size_t)BK * N;
  }
#pragma unroll
  for (int i = 0; i < 5; i++)
    *(ushort4*)(bs0 + woff[i]) =
        make_ushort4(f2bf_rn(bv[i][0]), f2bf_rn(bv[i][1]),
                     f2bf_rn(bv[i][2]), f2bf_rn(bv[i][3]));

  const unsigned short* arow0 = Ab + (size_t)(mrow + fr) * K + fq * 8;
  const unsigned short* arow1 = arow0 + 16 * K;

  for (int t = 0; t < NT; ++t) {
    const int cur = t & 1;
    if (t + 1 < NT) {          // issue next tile's loads (stay in flight
#pragma unroll                 // across the barrier and the MFMA phase)
      for (int i = 0; i < 5; i++) {
        const float* p = bp[i];
        bv[i][0] = p[0]; bv[i][1] = p[N];
        bv[i][2] = p[2 * (size_t)N]; bv[i][3] = p[3 * (size_t)N];
        bp[i] += (size_t)BK * N;
      }
    }
    __syncthreads();           // Bs[cur] visible; also separates prev reads
                               // of Bs[cur^1] from this iter's writes to it
#pragma unroll
    for (int ks = 0; ks < 4; ks++) {
      bf16x8 a0 = *(const bf16x8*)(arow0 + t * BK + ks * 32);
      bf16x8 a1 = *(const bf16x8*)(arow1 + t * BK + ks * 32);
#pragma unroll
      for (int ct = 0; ct < CT; ct++) {
        bf16x8 b = *(const bf16x8*)&Bs[cur][ct * 16 + fr][ks * 32 + fq * 8];
        acc[0][ct] = __builtin_amdgcn_mfma_f32_16x16x32_bf16(a0, b, acc[0][ct], 0, 0, 0);
        acc[1][ct] = __builtin_amdgcn_mfma_f32_16x16x32_bf16(a1, b, acc[1][ct], 0, 0, 0);
      }
    }
    if (t + 1 < NT) {          // convert + write AFTER compute (T14 late half)
      unsigned short* wb = bs0 + (cur ^ 1) * BUFS;
#pragma unroll
      for (int i = 0; i < 5; i++)
        *(ushort4*)(wb + woff[i]) =
            make_ushort4(f2bf_rn(bv[i][0]), f2bf_rn(bv[i][1]),
                         f2bf_rn(bv[i][2]), f2bf_rn(bv[i][3]));
    }
  }
  // epilogue: C/D layout col=lane&15, row=(lane>>4)*4+i
#pragma unroll
  for (int ct = 0; ct < CT; ct++) {
    const int c = n0 + ct * 16 + fr;
    const float bb = b3[c];
#pragma unroll
    for (int rt = 0; rt < 2; rt++) {
      const int r0 = mrow + rt * 16 + fq * 4;
#pragma unroll
      for (int i = 0; i < 4; i++)
        E[(size_t)(r0 + i) * N + c] = expf(acc[rt][ct][i] + bb);
    }
  }
}

// ---------------------------------------------------------------------------
// Fused grouped-softmax normalize: full 25000-gene denominator row in LDS
// (100 KB of the 160 KB/CU), one block per batch row. Pass 1: read E row,
// LDS-atomicAdd per gene. Pass 2: re-read (L2/L3-hot) and divide in place.
// Replaces denom_halves + div_kernel (saves the denom global round-trip and
// one full E pass).
// ---------------------------------------------------------------------------
__global__ __launch_bounds__(1024) void softmax_fused(
    float* __restrict__ E, const int* __restrict__ idx)
{
  __shared__ float dloc[NG];                 // 100000 B
  const int r = blockIdx.x;
  float4* Er = (float4*)(E + (size_t)r * NISO);
  const int4* I4 = (const int4*)idx;
  for (int j = threadIdx.x; j < NG; j += 1024) dloc[j] = 0.f;
  __syncthreads();
  for (int q = threadIdx.x; q < NISO / 4; q += 1024) {
    float4 v = Er[q]; int4 g = I4[q];
    atomicAdd(&dloc[g.x], v.x);
    atomicAdd(&dloc[g.y], v.y);
    atomicAdd(&dloc[g.z], v.z);
    atomicAdd(&dloc[g.w], v.w);
  }
  __syncthreads();
  for (int q = threadIdx.x; q < NISO / 4; q += 1024) {
    float4 v = Er[q]; int4 g = I4[q];
    v.x /= fmaxf(dloc[g.x], 1e-8f);
    v.y /= fmaxf(dloc[g.y], 1e-8f);
    v.z /= fmaxf(dloc[g.z], 1e-8f);
    v.w /= fmaxf(dloc[g.w], 1e-8f);
    Er[q] = v;
  }
}

// ---------------------------------------------------------------------------
extern "C" void kernel_launch(void* const* d_in, const int* in_sizes, int n_in,
                              void* d_out, int out_size, void* d_ws, size_t ws_size,
                              hipStream_t stream) {
  const float* x   = (const float*)d_in[0];
  const int*   idx = (const int*)  d_in[1];
  const float* W1  = (const float*)d_in[2];
  const float* b1  = (const float*)d_in[3];
  const float* g1  = (const float*)d_in[4];
  const float* be1 = (const float*)d_in[5];
  const float* W2  = (const float*)d_in[6];
  const float* b2  = (const float*)d_in[7];
  const float* g2  = (const float*)d_in[8];
  const float* be2 = (const float*)d_in[9];
  const float* W3  = (const float*)d_in[10];
  const float* b3  = (const float*)d_in[11];
  float* out = (float*)d_out;

  // workspace layout (floats), ~17.3 MB; everything fully overwritten
  // before read -> no memset needed.
  float* ws      = (float*)d_ws;
  float* h1slab  = ws;                                   // 5 * 256*2048
  float* h2slab  = h1slab + (size_t)5 * NB * NH1;        // 4 * 256*1024
  float* h1      = h2slab + (size_t)4 * NB * NH2;        // 256*2048
  unsigned short* h2b = (unsigned short*)(h1 + (size_t)NB * NH1);  // 256*1024 bf16

  // layer 1: x @ W1 (split-bf16, K=5000 in 5 slabs of 1000)
  gemm_split<128><<<dim3(NH1 / 128, NB / 64, 5), 256, 0, stream>>>(
      x, W1, h1slab, NB, NH1, DIN, 1000);
  ln_gelu_sum<false><<<NB, 256, 0, stream>>>(h1slab, 5, b1, g1, be1, h1, NH1);

  // layer 2: h1 @ W2 (split-bf16, K=2048 in 4 slabs of 512); output bf16
  gemm_split<128><<<dim3(NH2 / 128, NB / 64, 4), 256, 0, stream>>>(
      h1, W2, h2slab, NB, NH2, NH1, 512);
  ln_gelu_sum<true><<<NB, 256, 0, stream>>>(h2slab, 4, b2, g2, be2, h2b, NH2);

  // layer 3: h2b @ W3 + b3 -> exp -> E (=d_out)
  gemm3_exp<80><<<NISO / 80, 512, 0, stream>>>(h2b, W3, b3, out);

  // grouped-softmax normalization, fused denom+divide, in place on d_out
  softmax_fused<<<NB, 1024, 0, stream>>>(out, idx);
}

// Round 2
// 910.986 us; speedup vs baseline: 1.2825x; 1.1300x over previous
//
#include <hip/hip_runtime.h>
#include <math.h>

// Problem constants
#define NB   256      // batch rows
#define DIN  5000
#define NH1  2048
#define NH2  1024
#define NISO 100000
#define NG   25000

typedef __attribute__((ext_vector_type(8))) short bf16x8;
typedef __attribute__((ext_vector_type(4))) float f32x4;

__device__ __forceinline__ unsigned short f2bf_rn(float f) {
  union { float f; unsigned u; } v; v.f = f;
  unsigned r = v.u + 0x7FFFu + ((v.u >> 16) & 1u);
  return (unsigned short)(r >> 16);
}
__device__ __forceinline__ float bf2f(unsigned short h) {
  union { unsigned u; float f; } v; v.u = ((unsigned)h) << 16;
  return v.f;
}

// ---------------------------------------------------------------------------
// Split-bf16 (3-term) GEMM: ~fp32 accuracy via hi/lo decomposition.
// A [M x K] row-major fp32, B [K x N] row-major fp32.
// Each blockIdx.z writes its own C slab (no atomics, no zero-init needed);
// the LN kernel sums the slabs.
// grid = (N/BN, M/64, nz), block = 256 (4 waves x 16 rows). BM fixed at 64.
// Staging: all 18 global loads issued to registers BEFORE any convert
// (hides HBM latency under conversion VALU, T14-style).
// ---------------------------------------------------------------------------
template<int BN>
__global__ __launch_bounds__(256) void gemm_split(
    const float* __restrict__ A, const float* __restrict__ Bg,
    float* __restrict__ C, int M, int N, int K, int KC)
{
  constexpr int BM = 64;
  constexpr int BK = 32;
  constexpr int LDT = BK + 8;       // pad keeps b128 alignment, breaks pow2 stride
  constexpr int CT = BN / 16;
  constexpr int AT = BM * 8 / 256;  // A staging tasks per thread (2)
  constexpr int BT = BN * 8 / 256;  // B staging tasks per thread (4 @ BN=128)
  __shared__ unsigned short Ah[BM][LDT], Al[BM][LDT];
  __shared__ unsigned short Bh[BN][LDT], Bl[BN][LDT];
  const int tid = threadIdx.x;
  const int wave = tid >> 6, lane = tid & 63;
  const int fr = lane & 15, fq = lane >> 4;
  const int n0 = blockIdx.x * BN, m0 = blockIdx.y * BM;
  const int kb0 = blockIdx.z * KC;
  const int ke = min(kb0 + KC, K);
  const int mrow = wave * 16;
  float* Cz = C + (size_t)blockIdx.z * M * N;

  f32x4 acc[CT];
#pragma unroll
  for (int i = 0; i < CT; i++) acc[i] = (f32x4){0.f, 0.f, 0.f, 0.f};

  for (int kb = kb0; kb < ke; kb += BK) {
    // ---- load phase: issue ALL global loads into registers first ----
    float4 av[AT];
#pragma unroll
    for (int u = 0; u < AT; u++) {
      int s = tid + u * 256;
      int m = s >> 3, kq = (s & 7) * 4;
      int gk = kb + kq;
      const float* ap = A + (size_t)(m0 + m) * K + gk;
      float4 v;
      if (gk + 3 < ke) v = *(const float4*)ap;
      else {
        v.x = (gk     < ke) ? ap[0] : 0.f;
        v.y = (gk + 1 < ke) ? ap[1] : 0.f;
        v.z = (gk + 2 < ke) ? ap[2] : 0.f;
        v.w = (gk + 3 < ke) ? ap[3] : 0.f;
      }
      av[u] = v;
    }
    float bw[BT][4];
#pragma unroll
    for (int u = 0; u < BT; u++) {
      int s = tid + u * 256;
      int n = s % BN, k0 = (s / BN) * 4;
#pragma unroll
      for (int j = 0; j < 4; j++) {
        int gk = kb + k0 + j;
        bw[u][j] = (gk < ke) ? Bg[(size_t)gk * N + n0 + n] : 0.f;
      }
    }
    // ---- convert + LDS store phase ----
#pragma unroll
    for (int u = 0; u < AT; u++) {
      int s = tid + u * 256;
      int m = s >> 3, kq = (s & 7) * 4;
      float4 v = av[u];
      unsigned short h0 = f2bf_rn(v.x), h1 = f2bf_rn(v.y),
                     h2 = f2bf_rn(v.z), h3 = f2bf_rn(v.w);
      *(ushort4*)&Ah[m][kq] = make_ushort4(h0, h1, h2, h3);
      *(ushort4*)&Al[m][kq] = make_ushort4(f2bf_rn(v.x - bf2f(h0)),
                                           f2bf_rn(v.y - bf2f(h1)),
                                           f2bf_rn(v.z - bf2f(h2)),
                                           f2bf_rn(v.w - bf2f(h3)));
    }
#pragma unroll
    for (int u = 0; u < BT; u++) {
      int s = tid + u * 256;
      int n = s % BN, k0 = (s / BN) * 4;
      unsigned short hh[4], ll[4];
#pragma unroll
      for (int j = 0; j < 4; j++) {
        hh[j] = f2bf_rn(bw[u][j]);
        ll[j] = f2bf_rn(bw[u][j] - bf2f(hh[j]));
      }
      *(ushort4*)&Bh[n][k0] = make_ushort4(hh[0], hh[1], hh[2], hh[3]);
      *(ushort4*)&Bl[n][k0] = make_ushort4(ll[0], ll[1], ll[2], ll[3]);
    }
    __syncthreads();
    bf16x8 ah = *(const bf16x8*)&Ah[mrow + fr][fq * 8];
    bf16x8 al = *(const bf16x8*)&Al[mrow + fr][fq * 8];
#pragma unroll
    for (int ct = 0; ct < CT; ct++) {
      bf16x8 bh = *(const bf16x8*)&Bh[ct * 16 + fr][fq * 8];
      bf16x8 bl = *(const bf16x8*)&Bl[ct * 16 + fr][fq * 8];
      acc[ct] = __builtin_amdgcn_mfma_f32_16x16x32_bf16(ah, bh, acc[ct], 0, 0, 0);
      acc[ct] = __builtin_amdgcn_mfma_f32_16x16x32_bf16(ah, bl, acc[ct], 0, 0, 0);
      acc[ct] = __builtin_amdgcn_mfma_f32_16x16x32_bf16(al, bh, acc[ct], 0, 0, 0);
    }
    __syncthreads();
  }
  // epilogue: C/D layout col=lane&15, row=(lane>>4)*4+i ; plain stores
#pragma unroll
  for (int ct = 0; ct < CT; ct++) {
    int c = n0 + ct * 16 + fr;
    int r0 = m0 + mrow + fq * 4;
#pragma unroll
    for (int i = 0; i < 4; i++)
      Cz[(size_t)(r0 + i) * N + c] = acc[ct][i];
  }
}

// ---------------------------------------------------------------------------
// LayerNorm over summed split-K slabs (+bias, biased var, eps=1e-5) + exact
// GELU. One block (256 thr) per row. BF16OUT writes bf16 (consumed only by
// gemm3's A-fragment loads).
// ---------------------------------------------------------------------------
template<bool BF16OUT>
__global__ __launch_bounds__(256) void ln_gelu_sum(
    const float* __restrict__ slabs, int nslab,
    const float* __restrict__ bias, const float* __restrict__ gam,
    const float* __restrict__ beta, void* __restrict__ outp, int n)
{
  const int r = blockIdx.x;
  float vv[8];
  float s = 0.f, s2 = 0.f;
  int cnt = 0;
  for (int j = threadIdx.x; j < n; j += 256, cnt++) {
    float v = bias[j];
    for (int z = 0; z < nslab; z++)
      v += slabs[((size_t)z * NB + r) * n + j];
    vv[cnt] = v;
    s += v; s2 += v * v;
  }
#pragma unroll
  for (int o = 32; o > 0; o >>= 1) {
    s  += __shfl_down(s, o);
    s2 += __shfl_down(s2, o);
  }
  __shared__ float red[8];
  const int wave = threadIdx.x >> 6, lane = threadIdx.x & 63;
  if (lane == 0) { red[wave] = s; red[wave + 4] = s2; }
  __syncthreads();
  if (threadIdx.x == 0) {
    float ts = 0.f, t2 = 0.f;
    for (int w = 0; w < 4; w++) { ts += red[w]; t2 += red[w + 4]; }
    float mu = ts / n;
    float var = t2 / n - mu * mu;
    red[0] = mu; red[1] = rsqrtf(var + 1e-5f);
  }
  __syncthreads();
  const float mu = red[0], rs = red[1];
  cnt = 0;
  for (int j = threadIdx.x; j < n; j += 256, cnt++) {
    float v = (vv[cnt] - mu) * rs * gam[j] + beta[j];
    float g = 0.5f * v * (1.f + erff(v * 0.70710678118654752f));
    if (BF16OUT) ((unsigned short*)outp)[(size_t)r * n + j] = f2bf_rn(g);
    else         ((float*)outp)[(size_t)r * n + j] = g;
  }
}

// ---------------------------------------------------------------------------
// GEMM3 v3: h2b[256x1024 bf16] @ W3[1024x100000 fp32] + b3, exp epilogue.
//  - A fragments read directly from global (512 KB, L2-resident).
//  - B: 2-deep register double-buffer (bvE/bvO) + LDS double buffer.
//    Loads for tile t+2 are issued while tile t computes; the ds_write of
//    tile t+1 waits on loads issued a FULL tile earlier -> vmcnt stall gone.
//  - t-loop fully unrolled so all bvE/bvO indexing is static (no scratch).
//  - s_setprio(1) around MFMA cluster (co-resident blocks at different
//    phases -> scheduler favors MFMA-issuing waves).
// BM=256 (full M: W3 streamed exactly once), BN=80 -> 1250 blocks, BK=128.
// ---------------------------------------------------------------------------
#define G3_LOAD(bv)                                             \
  _Pragma("unroll")                                             \
  for (int i = 0; i < 5; i++) {                                 \
    const float* p = bp[i];                                     \
    bv[i][0] = p[0]; bv[i][1] = p[N];                           \
    bv[i][2] = p[2 * (size_t)N]; bv[i][3] = p[3 * (size_t)N];   \
    bp[i] += (size_t)BK * N;                                    \
  }
#define G3_WRITE(bv, wb)                                        \
  _Pragma("unroll")                                             \
  for (int i = 0; i < 5; i++)                                   \
    *(ushort4*)((wb) + woff[i]) =                               \
        make_ushort4(f2bf_rn(bv[i][0]), f2bf_rn(bv[i][1]),      \
                     f2bf_rn(bv[i][2]), f2bf_rn(bv[i][3]));

template<int BN>
__global__ __launch_bounds__(512, 4) void gemm3_exp(
    const unsigned short* __restrict__ Ab,  // h2 bf16 [256][1024]
    const float* __restrict__ Bg,           // W3
    const float* __restrict__ b3,
    float* __restrict__ E)                  // d_out, holds exp(logits)
{
  constexpr int BM = 256, BK = 128, K = NH2, N = NISO;
  constexpr int LDT = BK + 8;       // 136 shorts = 272 B row stride
  constexpr int CT = BN / 16;       // 5
  constexpr int NT = K / BK;        // 8 K-tiles
  constexpr int BUFS = BN * LDT;    // shorts per buffer
  __shared__ unsigned short Bs[2][BN][LDT];   // 2 x 21.25 KB
  const int tid = threadIdx.x;
  const int wave = tid >> 6, lane = tid & 63;
  const int fr = lane & 15, fq = lane >> 4;
  const int n0 = blockIdx.x * BN;
  const int mrow = wave * 32;       // 8 waves x 32 rows

  // B staging: s = tid + i*512 in [0, BN*BK/4): n = s%BN (coalesced along n),
  // k4 = s/BN (4 consecutive k rows per task).
  const float* bp[5];
  int woff[5];
#pragma unroll
  for (int i = 0; i < 5; i++) {
    int s = tid + i * 512;
    int n = s % BN, k4 = s / BN;
    bp[i] = Bg + (size_t)(4 * k4) * N + n0 + n;
    woff[i] = n * LDT + k4 * 4;
  }
  unsigned short* const bs0 = &Bs[0][0][0];
  float bvE[5][4], bvO[5][4];       // even / odd tile register buffers

  f32x4 acc[2][CT];
#pragma unroll
  for (int r = 0; r < 2; r++)
#pragma unroll
    for (int c = 0; c < CT; c++) acc[r][c] = (f32x4){0.f, 0.f, 0.f, 0.f};

  // prologue: tile0 -> bvE -> LDS buf0; tile1 -> bvO (stays in flight)
  G3_LOAD(bvE);
  G3_LOAD(bvO);
  G3_WRITE(bvE, bs0);

  const unsigned short* arow0 = Ab + (size_t)(mrow + fr) * K + fq * 8;
  const unsigned short* arow1 = arow0 + 16 * K;

#pragma unroll
  for (int t = 0; t < NT; ++t) {
    const int cur = t & 1;
    if (t + 2 < NT) {              // issue tile t+2 loads into the reg set
      if (cur == 0) { G3_LOAD(bvE); }   // whose data is already in LDS
      else          { G3_LOAD(bvO); }
    }
    __syncthreads();               // Bs[cur] visible; prior reads of
                                   // Bs[cur^1] complete
    __builtin_amdgcn_s_setprio(1);
#pragma unroll
    for (int ks = 0; ks < 4; ks++) {
      bf16x8 a0 = *(const bf16x8*)(arow0 + t * BK + ks * 32);
      bf16x8 a1 = *(const bf16x8*)(arow1 + t * BK + ks * 32);
#pragma unroll
      for (int ct = 0; ct < CT; ct++) {
        bf16x8 b = *(const bf16x8*)&Bs[cur][ct * 16 + fr][ks * 32 + fq * 8];
        acc[0][ct] = __builtin_amdgcn_mfma_f32_16x16x32_bf16(a0, b, acc[0][ct], 0, 0, 0);
        acc[1][ct] = __builtin_amdgcn_mfma_f32_16x16x32_bf16(a1, b, acc[1][ct], 0, 0, 0);
      }
    }
    __builtin_amdgcn_s_setprio(0);
    if (t + 1 < NT) {              // convert + write tile t+1 (loads issued
      unsigned short* wb = bs0 + (cur ^ 1) * BUFS;   // one full tile ago)
      if (cur == 0) { G3_WRITE(bvO, wb); }
      else          { G3_WRITE(bvE, wb); }
    }
  }
  // epilogue: C/D layout col=lane&15, row=(lane>>4)*4+i
#pragma unroll
  for (int ct = 0; ct < CT; ct++) {
    const int c = n0 + ct * 16 + fr;
    const float bb = b3[c];
#pragma unroll
    for (int rt = 0; rt < 2; rt++) {
      const int r0 = mrow + rt * 16 + fq * 4;
#pragma unroll
      for (int i = 0; i < 4; i++)
        E[(size_t)(r0 + i) * N + c] = expf(acc[rt][ct][i] + bb);
    }
  }
}

// ---------------------------------------------------------------------------
// Fused grouped-softmax normalize: full 25000-gene denominator row in LDS
// (100 KB), one block per batch row. Pass 1: read E row, LDS-atomicAdd per
// gene. Pass 2: re-read (L3-hot, E=102MB < 256MB L3) and divide in place.
// ---------------------------------------------------------------------------
__global__ __launch_bounds__(1024) void softmax_fused(
    float* __restrict__ E, const int* __restrict__ idx)
{
  __shared__ float dloc[NG];                 // 100000 B
  const int r = blockIdx.x;
  float4* Er = (float4*)(E + (size_t)r * NISO);
  const int4* I4 = (const int4*)idx;
  for (int j = threadIdx.x; j < NG; j += 1024) dloc[j] = 0.f;
  __syncthreads();
  for (int q = threadIdx.x; q < NISO / 4; q += 1024) {
    float4 v = Er[q]; int4 g = I4[q];
    atomicAdd(&dloc[g.x], v.x);
    atomicAdd(&dloc[g.y], v.y);
    atomicAdd(&dloc[g.z], v.z);
    atomicAdd(&dloc[g.w], v.w);
  }
  __syncthreads();
  for (int q = threadIdx.x; q < NISO / 4; q += 1024) {
    float4 v = Er[q]; int4 g = I4[q];
    v.x /= fmaxf(dloc[g.x], 1e-8f);
    v.y /= fmaxf(dloc[g.y], 1e-8f);
    v.z /= fmaxf(dloc[g.z], 1e-8f);
    v.w /= fmaxf(dloc[g.w], 1e-8f);
    Er[q] = v;
  }
}

// ---------------------------------------------------------------------------
extern "C" void kernel_launch(void* const* d_in, const int* in_sizes, int n_in,
                              void* d_out, int out_size, void* d_ws, size_t ws_size,
                              hipStream_t stream) {
  const float* x   = (const float*)d_in[0];
  const int*   idx = (const int*)  d_in[1];
  const float* W1  = (const float*)d_in[2];
  const float* b1  = (const float*)d_in[3];
  const float* g1  = (const float*)d_in[4];
  const float* be1 = (const float*)d_in[5];
  const float* W2  = (const float*)d_in[6];
  const float* b2  = (const float*)d_in[7];
  const float* g2  = (const float*)d_in[8];
  const float* be2 = (const float*)d_in[9];
  const float* W3  = (const float*)d_in[10];
  const float* b3  = (const float*)d_in[11];
  float* out = (float*)d_out;

  // workspace layout (floats), ~32 MB; everything fully overwritten
  // before read -> no memset needed.
  float* ws      = (float*)d_ws;
  float* h1slab  = ws;                                   // 10 * 256*2048
  float* h2slab  = h1slab + (size_t)10 * NB * NH1;       // 8 * 256*1024
  float* h1      = h2slab + (size_t)8 * NB * NH2;        // 256*2048
  unsigned short* h2b = (unsigned short*)(h1 + (size_t)NB * NH1);  // 256*1024 bf16

  // layer 1: x @ W1 (split-bf16, K=5000 in 10 slabs of 500 -> 640 blocks,
  // ~2.5/CU so staging latency overlaps across co-resident blocks)
  gemm_split<128><<<dim3(NH1 / 128, NB / 64, 10), 256, 0, stream>>>(
      x, W1, h1slab, NB, NH1, DIN, 500);
  ln_gelu_sum<false><<<NB, 256, 0, stream>>>(h1slab, 10, b1, g1, be1, h1, NH1);

  // layer 2: h1 @ W2 (split-bf16, K=2048 in 8 slabs of 256 -> 256 blocks,
  // one per CU; was 128 blocks = half the chip idle); output bf16
  gemm_split<128><<<dim3(NH2 / 128, NB / 64, 8), 256, 0, stream>>>(
      h1, W2, h2slab, NB, NH2, NH1, 256);
  ln_gelu_sum<true><<<NB, 256, 0, stream>>>(h2slab, 8, b2, g2, be2, h2b, NH2);

  // layer 3: h2b @ W3 + b3 -> exp -> E (=d_out)
  gemm3_exp<80><<<NISO / 80, 512, 0, stream>>>(h2b, W3, b3, out);

  // grouped-softmax normalization, fused denom+divide, in place on d_out
  softmax_fused<<<NB, 1024, 0, stream>>>(out, idx);
}